// Round 9
// baseline (25707.892 us; speedup 1.0000x reference)
//
#include <hip/hip_runtime.h>

#define B 64
#define T 2048
#define D 128
#define H 256
#define H2 512
#define NP 4
#define CHUNK 8

// workspace: per row 1536 u64 tagged slots:
//   [0..255] c | [256..511] o | [512..1535] hpre (4 parts x 256 partials)
// value = low 32 bits (float bits), seq tag = high 32 bits.
#define ROW_U64 1536
#define WS_NEEDED ((size_t)B * ROW_U64 * 8)
#define SPIN_LIM (1 << 20)

__device__ __forceinline__ float sigmoid_f(float x) { return 1.f / (1.f + __expf(-x)); }
__device__ __forceinline__ float tanh_f(float x) {
    float e = __expf(2.f * x);
    return 1.f - 2.f / (e + 1.f);
}
__device__ __forceinline__ unsigned long long pack_tag(float v, unsigned int tag) {
    return ((unsigned long long)tag << 32) | (unsigned long long)__float_as_uint(v);
}
__device__ __forceinline__ float poll_tagged(const unsigned long long* __restrict__ ptr,
                                             unsigned int tag, bool& alive) {
    unsigned long long v;
    if (alive) {
        int cnt = 0;
        do {
            v = __hip_atomic_load(ptr, __ATOMIC_RELAXED, __HIP_MEMORY_SCOPE_AGENT);
            if ((unsigned int)(v >> 32) == tag)
                return __uint_as_float((unsigned int)v);
        } while (++cnt < SPIN_LIM);
        alive = false;   // latch: never spin again, accept wrong data over a hang
    }
    v = __hip_atomic_load(ptr, __ATOMIC_RELAXED, __HIP_MEMORY_SCOPE_AGENT);
    return __uint_as_float((unsigned int)v);
}

#define FMA4(A_, S_, W_) \
    A_.x = fmaf(S_, W_.x, A_.x); A_.y = fmaf(S_, W_.y, A_.y); \
    A_.z = fmaf(S_, W_.z, A_.z); A_.w = fmaf(S_, W_.w, A_.w);

// 256 blocks = 64 rows x 4 column-parts; 512 threads; 1 block/CU (LDS-forced).
// vs R8:
//  - K2 layout conflict-free: col = wave*32 + (lane&31), kh = lane>>5 -> each
//    32-lane half-phase hits banks 0..31 once; reduce via __shfl_xor(,32)
//  - K2 k-range half in registers (k2r[32], static idx); LDS slice 64 rows (64KB)
//  - phase-P blob dissolved: ONE x@W slice per step for t+8, computed between
//    the hpre publish and the hpre poll (hidden under the exchange RTT)
__global__ __launch_bounds__(512) void scan_kernel(
    const float* __restrict__ x,
    const float* __restrict__ Wi, const float* __restrict__ bi,
    const float* __restrict__ Wf, const float* __restrict__ bf,
    const float* __restrict__ Wc, const float* __restrict__ bc,
    const float* __restrict__ Wo, const float* __restrict__ bo,
    const float* __restrict__ Ui, const float* __restrict__ Uf,
    const float* __restrict__ Uc, const float* __restrict__ Uo,
    const float* __restrict__ K1, const float* __restrict__ kb1,
    const float* __restrict__ K2, const float* __restrict__ kb2,
    const float* __restrict__ gamma, const float* __restrict__ beta,
    float* __restrict__ out,
    unsigned long long* __restrict__ ws)
{
    const int bid = blockIdx.x;
    const int b   = bid >> 2;
    const int p   = bid & 3;
    const int tid = threadIdx.x;

    __shared__ float k2lds2[64 * 256];    // 64 KB: K2 rows {p*128+kh*64+32..63}, kh=0,1
    __shared__ float xw[CHUNK][256];      // 8 KB
    __shared__ float red[2048];           // 8 KB
    __shared__ float hs[H], cs[H], os[H], us[H], ts[128];

    // ---- roles ----
    const int kq  = tid >> 6;                              // 0..7 (wave)
    const int grp = tid & 63;
    const int gG  = grp >> 4;                              // gate 0..3
    const int jG  = (grp & 15) * 4;                        // col-4 within part
    const int col = kq * 32 + (grp & 31);                  // K2 output col (0..255)
    const int kh  = grp >> 5;                              // K2 k-half (half-phase split!)
    const int kh64 = kh * 64;

    const float* Ug = (gG == 0) ? Ui : (gG == 1) ? Uf : (gG == 2) ? Uc : Uo;
    const float* Wg = (gG == 0) ? Wi : (gG == 1) ? Wf : (gG == 2) ? Wc : Wo;

    // ---- register-resident U quarter ----
    float4 uw[32];                                    // U: 32 k x 4 cols
    #pragma unroll
    for (int k = 0; k < 32; ++k)
        uw[k] = *(const float4*)(Ug + (size_t)(kq * 32 + k) * H + p * 64 + jG);

    // ---- register-resident K1 quarter, pre-rotated (rule #20: static reg idx) ----
    const int c1  = tid >> 2;
    const int ks  = tid & 3;
    float4 k1w[16];
    #pragma unroll
    for (int i = 0; i < 16; ++i) {
        const int j = (i + ks * 2) & 15;              // runtime addr component only
        float4 v;
        v.x = K1[(size_t)(ks * 64 + j * 4 + 0) * H2 + p * 128 + c1];
        v.y = K1[(size_t)(ks * 64 + j * 4 + 1) * H2 + p * 128 + c1];
        v.z = K1[(size_t)(ks * 64 + j * 4 + 2) * H2 + p * 128 + c1];
        v.w = K1[(size_t)(ks * 64 + j * 4 + 3) * H2 + p * 128 + c1];
        k1w[i] = v;
    }

    // ---- K2 register half: k = kh*64 + 0..31 for this thread's col ----
    float k2r[32];
    #pragma unroll
    for (int kk = 0; kk < 32; ++kk)
        k2r[kk] = K2[(size_t)(p * 128 + kh64 + kk) * H + col];

    // ---- K2 LDS half: rows kh*64+32..63 -> ldsrow kh*32 + 0..31 ----
    for (int idx = tid; idx < 64 * 64; idx += 512) {
        int k = idx >> 6, jg = (idx & 63) * 4;
        int grow = (k >> 5) * 64 + 32 + (k & 31);
        *(float4*)&k2lds2[k * 256 + jg] =
            *(const float4*)(K2 + (size_t)(p * 128 + grow) * H + jg);
    }

    // ---- per-role constants ----
    float bcat = 0.f;
    const float kb1r = kb1[p * 128 + c1];
    const float kb2r = kb2[col];
    float4 gam4, bet4;
    if (tid < 256) {
        const int g = tid >> 6, jj = tid & 63;
        const float* bp = (g == 0) ? bi : (g == 1) ? bf : (g == 2) ? bc : bo;
        bcat = bp[p * 64 + jj];
    }
    if (tid < 64) {
        gam4 = *(const float4*)(gamma + tid * 4);
        bet4 = *(const float4*)(beta + tid * 4);
    }

    if (tid < 256) hs[tid] = 0.f;
    float c_reg = 0.f;                   // lane j (tid<64) carries c[p*64+j]

    const float* xrow = x + (size_t)b * T * D;
    float* yb = out + (size_t)b * T * H;
    unsigned long long* rowp  = ws + (size_t)b * ROW_U64;
    unsigned long long* slotC = rowp;
    unsigned long long* slotO = rowp + 256;
    unsigned long long* slotH = rowp + 512;            // [part*256 + j]
    const int dqu = __builtin_amdgcn_readfirstlane(kq);   // uniform d-slice for x s_loads

    bool alive = true;
    __syncthreads();

    // ---- prologue: prefill xw for chunk 0 ----
    for (int r8 = 0; r8 < CHUNK; ++r8) {
        float4 acc = make_float4(0.f, 0.f, 0.f, 0.f);
        const float* Wp = Wg + p * 64 + jG;
        #pragma unroll 4
        for (int dd = 0; dd < 16; ++dd) {
            const int d = dqu * 16 + dd;
            float4 w = *(const float4*)(Wp + (size_t)d * H);
            float xv = xrow[(size_t)r8 * D + d];
            FMA4(acc, xv, w);
        }
        *(float4*)&red[kq * 256 + grp * 4] = acc;
        __syncthreads();
        if (tid < 256) {
            float s = bcat;
            #pragma unroll
            for (int q = 0; q < 8; ++q) s += red[q * 256 + tid];
            xw[r8][tid] = s;
        }
        __syncthreads();
    }

    for (int t = 0; t < T; ++t) {
        const int tt8 = t & (CHUNK - 1);
        const unsigned int seq = (unsigned int)(t + 1);
        const int tx = t + CHUNK;                      // step whose xw we pipeline

        // ============ G: gate preacts from register-resident U (dump) ============
        {
            float4 a = make_float4(0.f, 0.f, 0.f, 0.f);
            #pragma unroll
            for (int k4 = 0; k4 < 8; ++k4) {
                float4 hv = *(const float4*)&hs[kq * 32 + k4 * 4];
                FMA4(a, hv.x, uw[k4 * 4 + 0]);
                FMA4(a, hv.y, uw[k4 * 4 + 1]);
                FMA4(a, hv.z, uw[k4 * 4 + 2]);
                FMA4(a, hv.w, uw[k4 * 4 + 3]);
            }
            *(float4*)&red[kq * 256 + grp * 4] = a;
        }
        __syncthreads();

        // ============ cell + publish (tid<64) ; poll remote {c,o} (tid 64..447) ============
        if (tid < 64) {
            const int j = tid;
            float si = xw[tt8][j],        sf = xw[tt8][64 + j],
                  sg = xw[tt8][128 + j],  so = xw[tt8][192 + j];
            #pragma unroll
            for (int q = 0; q < 8; ++q) {
                si += red[q * 256 + j];
                sf += red[q * 256 + 64 + j];
                sg += red[q * 256 + 128 + j];
                so += red[q * 256 + 192 + j];
            }
            float iv = sigmoid_f(si), fv = sigmoid_f(sf);
            float gv = tanh_f(sg),    ov = sigmoid_f(so);
            float c = fmaf(fv, c_reg, iv * gv);
            c_reg = c;
            cs[p * 64 + j] = c;
            os[p * 64 + j] = ov;
            __hip_atomic_store(slotC + p * 64 + j, pack_tag(c, seq),
                               __ATOMIC_RELAXED, __HIP_MEMORY_SCOPE_AGENT);
            __hip_atomic_store(slotO + p * 64 + j, pack_tag(ov, seq),
                               __ATOMIC_RELAXED, __HIP_MEMORY_SCOPE_AGENT);
        } else if (tid < 448) {
            const int idx = tid - 64;                      // 0..383
            if (idx < 192) {
                const int q  = (p + 1 + (idx >> 6)) & 3;   // remote part
                const int gj = q * 64 + (idx & 63);
                cs[gj] = poll_tagged(slotC + gj, seq, alive);
            } else {
                const int i2 = idx - 192;
                const int q  = (p + 1 + (i2 >> 6)) & 3;
                const int gj = q * 64 + (i2 & 63);
                os[gj] = poll_tagged(slotO + gj, seq, alive);
            }
        }
        __syncthreads();

        // ============ K1+ts fused: 4 threads/output, rotated LDS addr, quad shuffle ====
        {
            float a = 0.f;
            #pragma unroll
            for (int i = 0; i < 16; ++i) {
                const int j = (i + ks * 2) & 15;           // runtime LDS address only
                float4 cv = *(const float4*)&cs[ks * 64 + j * 4];
                a += cv.x * k1w[i].x + cv.y * k1w[i].y
                   + cv.z * k1w[i].z + cv.w * k1w[i].w;
            }
            a += __shfl_xor(a, 1);
            a += __shfl_xor(a, 2);
            if (ks == 0) ts[c1] = tanh_f(a + kb1r);
        }
        __syncthreads();

        // ============ K2 partial (regs + LDS, conflict-free) + publish ;
        //              then x@W slice for t+CHUNK (hidden under the RTT) ============
        float k2part = 0.f;
        {
            #pragma unroll
            for (int i = 0; i < 8; ++i) {
                float4 tv = *(const float4*)&ts[kh64 + i * 4];   // broadcast per half
                k2part = fmaf(tv.x, k2r[i * 4 + 0], k2part);
                k2part = fmaf(tv.y, k2r[i * 4 + 1], k2part);
                k2part = fmaf(tv.z, k2r[i * 4 + 2], k2part);
                k2part = fmaf(tv.w, k2r[i * 4 + 3], k2part);
            }
            const float* kp0 = &k2lds2[(kh * 32) * 256 + col];
            #pragma unroll
            for (int i = 0; i < 8; ++i) {
                float4 tv = *(const float4*)&ts[kh64 + 32 + i * 4];
                const float* kp = kp0 + i * 1024;
                k2part = fmaf(tv.x, kp[0],   k2part);   // bank = col%32: each half-phase
                k2part = fmaf(tv.y, kp[256], k2part);   // hits banks 0..31 exactly once
                k2part = fmaf(tv.z, kp[512], k2part);
                k2part = fmaf(tv.w, kp[768], k2part);
            }
            k2part += __shfl_xor(k2part, 32);          // kh partner is lane^32
            if (kh == 0)
                __hip_atomic_store(slotH + p * 256 + col, pack_tag(k2part, seq),
                                   __ATOMIC_RELAXED, __HIP_MEMORY_SCOPE_AGENT);
            if (tx < T) {                               // x@W slice for step t+CHUNK
                float4 acc = make_float4(0.f, 0.f, 0.f, 0.f);
                const float* Wp = Wg + p * 64 + jG;
                #pragma unroll 4
                for (int dd = 0; dd < 16; ++dd) {
                    const int d = dqu * 16 + dd;
                    float4 w = *(const float4*)(Wp + (size_t)d * H);
                    float xv = xrow[(size_t)tx * D + d];   // uniform -> s_load
                    FMA4(acc, xv, w);
                }
                *(float4*)&red[kq * 256 + grp * 4] = acc;
            }
        }
        __syncthreads();

        // ============ xw reduce ; poll hpre -> u (kh==0 lanes) ============
        if (tx < T && tid < 256) {
            float s = bcat;
            #pragma unroll
            for (int q = 0; q < 8; ++q) s += red[q * 256 + tid];
            xw[tt8][tid] = s;
        }
        if (kh == 0) {
            const unsigned long long* q1 = slotH + (((p + 1) & 3) << 8) + col;
            const unsigned long long* q2 = slotH + (((p + 2) & 3) << 8) + col;
            const unsigned long long* q3 = slotH + (((p + 3) & 3) << 8) + col;
            unsigned long long v1 = 0, v2 = 0, v3 = 0;
            bool d1 = false, d2 = false, d3 = false;
            int cnt = 0;
            const int lim = alive ? SPIN_LIM : 2;
            while (true) {   // 3 loads in flight per iteration
                if (!d1) v1 = __hip_atomic_load(q1, __ATOMIC_RELAXED, __HIP_MEMORY_SCOPE_AGENT);
                if (!d2) v2 = __hip_atomic_load(q2, __ATOMIC_RELAXED, __HIP_MEMORY_SCOPE_AGENT);
                if (!d3) v3 = __hip_atomic_load(q3, __ATOMIC_RELAXED, __HIP_MEMORY_SCOPE_AGENT);
                d1 = d1 | ((unsigned int)(v1 >> 32) == seq);
                d2 = d2 | ((unsigned int)(v2 >> 32) == seq);
                d3 = d3 | ((unsigned int)(v3 >> 32) == seq);
                if (d1 & d2 & d3) break;
                if (++cnt > lim) { alive = false; break; }
            }
            float hp = k2part + __uint_as_float((unsigned int)v1)
                              + __uint_as_float((unsigned int)v2)
                              + __uint_as_float((unsigned int)v3) + kb2r;
            us[col] = os[col] * tanh_f(hp);
        }
        __syncthreads();

        // ============ LayerNorm (replicated; full u local) ============
        if (tid < 64) {
            float4 u4 = *(const float4*)&us[tid * 4];
            float s1 = u4.x + u4.y + u4.z + u4.w;
            float s2 = u4.x * u4.x + u4.y * u4.y + u4.z * u4.z + u4.w * u4.w;
            #pragma unroll
            for (int off = 32; off > 0; off >>= 1) {
                s1 += __shfl_xor(s1, off);
                s2 += __shfl_xor(s2, off);
            }
            float mu   = s1 * (1.f / 256.f);
            float var  = fmaf(-mu, mu, s2 * (1.f / 256.f));
            float rstd = rsqrtf(var + 1e-5f);
            float4 hn;
            hn.x = (u4.x - mu) * rstd * gam4.x + bet4.x;
            hn.y = (u4.y - mu) * rstd * gam4.y + bet4.y;
            hn.z = (u4.z - mu) * rstd * gam4.z + bet4.z;
            hn.w = (u4.w - mu) * rstd * gam4.w + bet4.w;
            *(float4*)&hs[tid * 4] = hn;
            if ((tid >> 4) == p) {   // own column slice only
                *(float4*)(yb + (size_t)t * H + tid * 4) = hn;
                if (t == T - 1) {
                    *(float4*)(out + (size_t)B * T * H + (size_t)b * H + tid * 4) = hn;
                    float4 c4 = *(const float4*)&cs[tid * 4];
                    *(float4*)(out + (size_t)B * T * H + (size_t)B * H + (size_t)b * H + tid * 4) = c4;
                }
            }
        }
        __syncthreads();   // hs ready for next step's G
    }
}

extern "C" void kernel_launch(void* const* d_in, const int* in_sizes, int n_in,
                              void* d_out, int out_size, void* d_ws, size_t ws_size,
                              hipStream_t stream) {
    (void)in_sizes; (void)n_in; (void)out_size;
    if (ws_size < WS_NEEDED) return;

    const float* x     = (const float*)d_in[0];
    const float* Wi    = (const float*)d_in[1];
    const float* bi    = (const float*)d_in[2];
    const float* Wf    = (const float*)d_in[3];
    const float* bf    = (const float*)d_in[4];
    const float* Wc    = (const float*)d_in[5];
    const float* bc    = (const float*)d_in[6];
    const float* Wo    = (const float*)d_in[7];
    const float* bo    = (const float*)d_in[8];
    const float* Ui    = (const float*)d_in[9];
    const float* Uf    = (const float*)d_in[10];
    const float* Uc    = (const float*)d_in[11];
    const float* Uo    = (const float*)d_in[12];
    const float* K1    = (const float*)d_in[13];
    const float* kb1   = (const float*)d_in[14];
    const float* K2    = (const float*)d_in[15];
    const float* kb2   = (const float*)d_in[16];
    const float* gamma = (const float*)d_in[17];
    const float* beta  = (const float*)d_in[18];
    float* out = (float*)d_out;

    scan_kernel<<<dim3(B * NP), dim3(512), 0, stream>>>(
        x, Wi, bi, Wf, bf, Wc, bc, Wo, bo,
        Ui, Uf, Uc, Uo, K1, kb1, K2, kb2, gamma, beta, out,
        (unsigned long long*)d_ws);
}

// Round 10
// 14642.963 us; speedup vs baseline: 1.7556x; 1.7556x over previous
//
#include <hip/hip_runtime.h>

#define B 64
#define T 2048
#define D 128
#define H 256
#define H2 512
#define NP 4
#define CHUNK 8

// workspace: per row 1536 u64 tagged slots:
//   [0..255] c | [256..511] o | [512..1535] hpre (4 parts x 256 partials)
// value = low 32 bits (float bits), seq tag = high 32 bits.
#define ROW_U64 1536
#define WS_NEEDED ((size_t)B * ROW_U64 * 8)
#define SPIN_LIM (1 << 20)

__device__ __forceinline__ float sigmoid_f(float x) { return 1.f / (1.f + __expf(-x)); }
__device__ __forceinline__ float tanh_f(float x) {
    float e = __expf(2.f * x);
    return 1.f - 2.f / (e + 1.f);
}
__device__ __forceinline__ unsigned long long pack_tag(float v, unsigned int tag) {
    return ((unsigned long long)tag << 32) | (unsigned long long)__float_as_uint(v);
}
__device__ __forceinline__ float poll_tagged(const unsigned long long* __restrict__ ptr,
                                             unsigned int tag, bool& alive) {
    unsigned long long v;
    if (alive) {
        int cnt = 0;
        do {
            v = __hip_atomic_load(ptr, __ATOMIC_RELAXED, __HIP_MEMORY_SCOPE_AGENT);
            if ((unsigned int)(v >> 32) == tag)
                return __uint_as_float((unsigned int)v);
        } while (++cnt < SPIN_LIM);
        alive = false;   // latch: never spin again, accept wrong data over a hang
    }
    v = __hip_atomic_load(ptr, __ATOMIC_RELAXED, __HIP_MEMORY_SCOPE_AGENT);
    return __uint_as_float((unsigned int)v);
}

#define FMA4(A_, S_, W_) \
    A_.x = fmaf(S_, W_.x, A_.x); A_.y = fmaf(S_, W_.y, A_.y); \
    A_.z = fmaf(S_, W_.z, A_.z); A_.w = fmaf(S_, W_.w, A_.w);

// 256 blocks = 64 rows x 4 column-parts; 512 threads; 1 block/CU (LDS-forced).
// R8 base (best: 15.30 ms) with ONE change: K2 worker mapping is
// col = wave*32 + (lane&31), kh = lane>>5 -> each 32-lane half-phase hits
// banks 0..31 exactly once (R8's kh=tid&1 paired 2 addresses/bank in-phase,
// 8.05e8 conflict cycles). Reduce via __shfl_xor(,32). No new registers
// (R9's k2r[32] blew the 256/lane unified budget -> scratch, 25.7 ms).
__global__ __launch_bounds__(512) void scan_kernel(
    const float* __restrict__ x,
    const float* __restrict__ Wi, const float* __restrict__ bi,
    const float* __restrict__ Wf, const float* __restrict__ bf,
    const float* __restrict__ Wc, const float* __restrict__ bc,
    const float* __restrict__ Wo, const float* __restrict__ bo,
    const float* __restrict__ Ui, const float* __restrict__ Uf,
    const float* __restrict__ Uc, const float* __restrict__ Uo,
    const float* __restrict__ K1, const float* __restrict__ kb1,
    const float* __restrict__ K2, const float* __restrict__ kb2,
    const float* __restrict__ gamma, const float* __restrict__ beta,
    float* __restrict__ out,
    unsigned long long* __restrict__ ws)
{
    const int bid = blockIdx.x;
    const int b   = bid >> 2;
    const int p   = bid & 3;
    const int tid = threadIdx.x;

    __shared__ float k2lds[128 * 256];    // 128 KB: K2 rows [p*128,+128), row-major [k][col]
    __shared__ float xw[CHUNK][256];      // 8 KB
    __shared__ float red[2048];           // 8 KB (phase P + phase G dumps)
    __shared__ float hs[H], cs[H], os[H], us[H], ts[128];

    // ---- roles ----
    const int kq  = tid >> 6;                              // 0..7 (wave)
    const int grp = tid & 63;
    const int gG  = grp >> 4;                              // gate 0..3
    const int jG  = (grp & 15) * 4;                        // col-4 within part
    const int col = kq * 32 + (grp & 31);                  // K2 output col (0..255)
    const int kh  = grp >> 5;                              // K2 k-half (half-phase split)
    const int kh64 = kh * 64;

    const float* Ug = (gG == 0) ? Ui : (gG == 1) ? Uf : (gG == 2) ? Uc : Uo;
    const float* Wg = (gG == 0) ? Wi : (gG == 1) ? Wf : (gG == 2) ? Wc : Wo;

    // ---- register-resident U quarter (as R3) ----
    float4 uw[32];                                    // U: 32 k x 4 cols
    #pragma unroll
    for (int k = 0; k < 32; ++k)
        uw[k] = *(const float4*)(Ug + (size_t)(kq * 32 + k) * H + p * 64 + jG);

    // ---- register-resident K1 quarter, pre-rotated (rule #20: static reg idx) ----
    const int c1  = tid >> 2;
    const int ks  = tid & 3;
    float4 k1w[16];
    #pragma unroll
    for (int i = 0; i < 16; ++i) {
        const int j = (i + ks * 2) & 15;              // runtime addr component only
        float4 v;
        v.x = K1[(size_t)(ks * 64 + j * 4 + 0) * H2 + p * 128 + c1];
        v.y = K1[(size_t)(ks * 64 + j * 4 + 1) * H2 + p * 128 + c1];
        v.z = K1[(size_t)(ks * 64 + j * 4 + 2) * H2 + p * 128 + c1];
        v.w = K1[(size_t)(ks * 64 + j * 4 + 3) * H2 + p * 128 + c1];
        k1w[i] = v;
    }

    // ---- K2 row-slice -> LDS, ROW-MAJOR (coalesced b128 stage, conflict-free) ----
    for (int idx = tid; idx < 128 * 64; idx += 512) {
        int k = idx >> 6, jg = (idx & 63) * 4;
        *(float4*)&k2lds[k * 256 + jg] = *(const float4*)(K2 + (size_t)(p * 128 + k) * H + jg);
    }

    // ---- per-role constants ----
    float bcat = 0.f;
    const float kb1r = kb1[p * 128 + c1];             // for K1 quad (ks==0 lanes use it)
    const float kb2r = kb2[col];                      // for K2 kh==0 lanes
    float4 gam4, bet4;
    if (tid < 256) {
        const int g = tid >> 6, jj = tid & 63;
        const float* bp = (g == 0) ? bi : (g == 1) ? bf : (g == 2) ? bc : bo;
        bcat = bp[p * 64 + jj];
    }
    if (tid < 64) {
        gam4 = *(const float4*)(gamma + tid * 4);
        bet4 = *(const float4*)(beta + tid * 4);
    }

    if (tid < 256) hs[tid] = 0.f;
    float c_reg = 0.f;                   // lane j (tid<64) carries c[p*64+j]

    const float* xrow = x + (size_t)b * T * D;
    float* yb = out + (size_t)b * T * H;
    unsigned long long* rowp  = ws + (size_t)b * ROW_U64;
    unsigned long long* slotC = rowp;
    unsigned long long* slotO = rowp + 256;
    unsigned long long* slotH = rowp + 512;            // [part*256 + j]
    const int dqu = __builtin_amdgcn_readfirstlane(kq);   // uniform d-slice for x s_loads

    bool alive = true;
    __syncthreads();

    for (int t = 0; t < T; ++t) {
        const int tt8 = t & (CHUNK - 1);
        const unsigned int seq = (unsigned int)(t + 1);

        // ============ phase P: x@W for 8 steps (once per chunk; W streamed) ============
        if (tt8 == 0) {
            const float* Wp = Wg + p * 64 + jG;
            #pragma unroll
            for (int pass = 0; pass < 2; ++pass) {
                float4 acc[4];
                #pragma unroll
                for (int r = 0; r < 4; ++r) acc[r] = make_float4(0.f, 0.f, 0.f, 0.f);
                #pragma unroll 4
                for (int dd = 0; dd < 16; ++dd) {
                    const int d = dqu * 16 + dd;
                    float4 w = *(const float4*)(Wp + (size_t)d * H);
                    #pragma unroll
                    for (int r = 0; r < 4; ++r) {
                        float xv = xrow[(size_t)(t + pass * 4 + r) * D + d];  // uniform -> s_load
                        FMA4(acc[r], xv, w);
                    }
                }
                #pragma unroll
                for (int r = 0; r < 4; ++r) {
                    *(float4*)&red[kq * 256 + grp * 4] = acc[r];
                    __syncthreads();
                    if (tid < 256) {
                        float s = bcat;
                        #pragma unroll
                        for (int q = 0; q < 8; ++q) s += red[q * 256 + tid];
                        xw[pass * 4 + r][tid] = s;
                    }
                    __syncthreads();
                }
            }
        }

        // ============ G: gate preacts from register-resident U (dump) ============
        {
            float4 a = make_float4(0.f, 0.f, 0.f, 0.f);
            #pragma unroll
            for (int k4 = 0; k4 < 8; ++k4) {
                float4 hv = *(const float4*)&hs[kq * 32 + k4 * 4];
                FMA4(a, hv.x, uw[k4 * 4 + 0]);
                FMA4(a, hv.y, uw[k4 * 4 + 1]);
                FMA4(a, hv.z, uw[k4 * 4 + 2]);
                FMA4(a, hv.w, uw[k4 * 4 + 3]);
            }
            *(float4*)&red[kq * 256 + grp * 4] = a;
        }
        __syncthreads();

        // ============ cell + publish (tid<64) ; poll remote {c,o} (tid 64..447) ============
        if (tid < 64) {
            const int j = tid;
            float si = xw[tt8][j],        sf = xw[tt8][64 + j],
                  sg = xw[tt8][128 + j],  so = xw[tt8][192 + j];
            #pragma unroll
            for (int q = 0; q < 8; ++q) {
                si += red[q * 256 + j];
                sf += red[q * 256 + 64 + j];
                sg += red[q * 256 + 128 + j];
                so += red[q * 256 + 192 + j];
            }
            float iv = sigmoid_f(si), fv = sigmoid_f(sf);
            float gv = tanh_f(sg),    ov = sigmoid_f(so);
            float c = fmaf(fv, c_reg, iv * gv);
            c_reg = c;
            cs[p * 64 + j] = c;
            os[p * 64 + j] = ov;
            __hip_atomic_store(slotC + p * 64 + j, pack_tag(c, seq),
                               __ATOMIC_RELAXED, __HIP_MEMORY_SCOPE_AGENT);
            __hip_atomic_store(slotO + p * 64 + j, pack_tag(ov, seq),
                               __ATOMIC_RELAXED, __HIP_MEMORY_SCOPE_AGENT);
        } else if (tid < 448) {
            const int idx = tid - 64;                      // 0..383
            if (idx < 192) {
                const int q  = (p + 1 + (idx >> 6)) & 3;   // remote part
                const int gj = q * 64 + (idx & 63);
                cs[gj] = poll_tagged(slotC + gj, seq, alive);
            } else {
                const int i2 = idx - 192;
                const int q  = (p + 1 + (i2 >> 6)) & 3;
                const int gj = q * 64 + (i2 & 63);
                os[gj] = poll_tagged(slotO + gj, seq, alive);
            }
        }
        __syncthreads();

        // ============ K1+ts fused: 4 threads/output, rotated LDS addr, quad shuffle ====
        {
            float a = 0.f;
            #pragma unroll
            for (int i = 0; i < 16; ++i) {
                const int j = (i + ks * 2) & 15;           // runtime LDS address only
                float4 cv = *(const float4*)&cs[ks * 64 + j * 4];
                a += cv.x * k1w[i].x + cv.y * k1w[i].y
                   + cv.z * k1w[i].z + cv.w * k1w[i].w;
            }
            a += __shfl_xor(a, 1);
            a += __shfl_xor(a, 2);
            if (ks == 0) ts[c1] = tanh_f(a + kb1r);
        }
        __syncthreads();

        // ============ K2 fused (conflict-free): half-phase col split, b32 over k
        //              (banks 0..31 once per half-phase), shfl_xor(32) reduce,
        //              kh==0 publishes partial, polls remotes, writes u ============
        {
            const float* kp0 = &k2lds[kh64 * 256 + col];
            float a = 0.f;
            #pragma unroll
            for (int i = 0; i < 16; ++i) {
                float4 tv = *(const float4*)&ts[kh64 + i * 4];   // broadcast per half-phase
                const float* kp = kp0 + i * 1024;
                a = fmaf(tv.x, kp[0],    a);
                a = fmaf(tv.y, kp[256],  a);
                a = fmaf(tv.z, kp[512],  a);
                a = fmaf(tv.w, kp[768],  a);
            }
            a += __shfl_xor(a, 32);                // kh partner is lane^32
            if (kh == 0) {
                __hip_atomic_store(slotH + p * 256 + col, pack_tag(a, seq),
                                   __ATOMIC_RELAXED, __HIP_MEMORY_SCOPE_AGENT);
                const unsigned long long* q1 = slotH + (((p + 1) & 3) << 8) + col;
                const unsigned long long* q2 = slotH + (((p + 2) & 3) << 8) + col;
                const unsigned long long* q3 = slotH + (((p + 3) & 3) << 8) + col;
                unsigned long long v1 = 0, v2 = 0, v3 = 0;
                bool d1 = false, d2 = false, d3 = false;
                int cnt = 0;
                const int lim = alive ? SPIN_LIM : 2;
                while (true) {   // 3 loads in flight per iteration
                    if (!d1) v1 = __hip_atomic_load(q1, __ATOMIC_RELAXED, __HIP_MEMORY_SCOPE_AGENT);
                    if (!d2) v2 = __hip_atomic_load(q2, __ATOMIC_RELAXED, __HIP_MEMORY_SCOPE_AGENT);
                    if (!d3) v3 = __hip_atomic_load(q3, __ATOMIC_RELAXED, __HIP_MEMORY_SCOPE_AGENT);
                    d1 = d1 | ((unsigned int)(v1 >> 32) == seq);
                    d2 = d2 | ((unsigned int)(v2 >> 32) == seq);
                    d3 = d3 | ((unsigned int)(v3 >> 32) == seq);
                    if (d1 & d2 & d3) break;
                    if (++cnt > lim) { alive = false; break; }
                }
                float hp = a + __uint_as_float((unsigned int)v1)
                             + __uint_as_float((unsigned int)v2)
                             + __uint_as_float((unsigned int)v3) + kb2r;
                us[col] = os[col] * tanh_f(hp);
            }
        }
        __syncthreads();

        // ============ LayerNorm (replicated; full u local) ============
        if (tid < 64) {
            float4 u4 = *(const float4*)&us[tid * 4];
            float s1 = u4.x + u4.y + u4.z + u4.w;
            float s2 = u4.x * u4.x + u4.y * u4.y + u4.z * u4.z + u4.w * u4.w;
            #pragma unroll
            for (int off = 32; off > 0; off >>= 1) {
                s1 += __shfl_xor(s1, off);
                s2 += __shfl_xor(s2, off);
            }
            float mu   = s1 * (1.f / 256.f);
            float var  = fmaf(-mu, mu, s2 * (1.f / 256.f));
            float rstd = rsqrtf(var + 1e-5f);
            float4 hn;
            hn.x = (u4.x - mu) * rstd * gam4.x + bet4.x;
            hn.y = (u4.y - mu) * rstd * gam4.y + bet4.y;
            hn.z = (u4.z - mu) * rstd * gam4.z + bet4.z;
            hn.w = (u4.w - mu) * rstd * gam4.w + bet4.w;
            *(float4*)&hs[tid * 4] = hn;
            if ((tid >> 4) == p) {   // own column slice only
                *(float4*)(yb + (size_t)t * H + tid * 4) = hn;
                if (t == T - 1) {
                    *(float4*)(out + (size_t)B * T * H + (size_t)b * H + tid * 4) = hn;
                    float4 c4 = *(const float4*)&cs[tid * 4];
                    *(float4*)(out + (size_t)B * T * H + (size_t)B * H + (size_t)b * H + tid * 4) = c4;
                }
            }
        }
        __syncthreads();   // hs ready for next step's G
    }
}

extern "C" void kernel_launch(void* const* d_in, const int* in_sizes, int n_in,
                              void* d_out, int out_size, void* d_ws, size_t ws_size,
                              hipStream_t stream) {
    (void)in_sizes; (void)n_in; (void)out_size;
    if (ws_size < WS_NEEDED) return;

    const float* x     = (const float*)d_in[0];
    const float* Wi    = (const float*)d_in[1];
    const float* bi    = (const float*)d_in[2];
    const float* Wf    = (const float*)d_in[3];
    const float* bf    = (const float*)d_in[4];
    const float* Wc    = (const float*)d_in[5];
    const float* bc    = (const float*)d_in[6];
    const float* Wo    = (const float*)d_in[7];
    const float* bo    = (const float*)d_in[8];
    const float* Ui    = (const float*)d_in[9];
    const float* Uf    = (const float*)d_in[10];
    const float* Uc    = (const float*)d_in[11];
    const float* Uo    = (const float*)d_in[12];
    const float* K1    = (const float*)d_in[13];
    const float* kb1   = (const float*)d_in[14];
    const float* K2    = (const float*)d_in[15];
    const float* kb2   = (const float*)d_in[16];
    const float* gamma = (const float*)d_in[17];
    const float* beta  = (const float*)d_in[18];
    float* out = (float*)d_out;

    scan_kernel<<<dim3(B * NP), dim3(512), 0, stream>>>(
        x, Wi, bi, Wf, bf, Wc, bc, Wo, bo,
        Ui, Uf, Uc, Uo, K1, kb1, K2, kb2, gamma, beta, out,
        (unsigned long long*)d_ws);
}